// Round 13
// baseline (208.438 us; speedup 1.0000x reference)
//
#include <hip/hip_runtime.h>

// Problem constants (match reference setup_inputs)
#define EDIM 128
#define NHEAD 4
#define NSEG 128
#define LOG2E 1.4426950408889634f
#define QPW 8

typedef float f32x4 __attribute__((ext_vector_type(4)));

// Round-12 post-mortem: MLP 1->8 all flat at ~66us pass1 (~2TB/s). Remaining
// suspect: per-instruction address pattern. Old map (lane -> 16 lanes/row,
// 32B/lane via f32x8) makes each dwordx4 instruction touch 32 cache lines at
// 16B-used-per-32B-sector. This round: PACKED loads — lane l reads float4 at
// byte l*16, one instr = 1KB contiguous, 16 lines, full sector use. Mapping:
// each 1KB load covers 2 rows (lane<32: row0, lane>=32: row1), lane owns dims
// 4*(l&31). Reduce = 4 DPP levels + shfl_xor(16) across the 32-lane half.

#define DOT4(xv, wv)                                                     \
    fmaf((xv)[3], (wv)[3], fmaf((xv)[2], (wv)[2],                        \
    fmaf((xv)[1], (wv)[1], (xv)[0] * (wv)[0])))

// 16-lane row sum via DPP (validated rounds 8-12): xor1 (quad_perm 0xB1),
// xor2 (0x4E), row_ror:4 (0x124), row_ror:8 (0x128).
__device__ __forceinline__ float dpp_add16(float v) {
    v += __int_as_float(__builtin_amdgcn_update_dpp(
        0, __float_as_int(v), 0xB1, 0xF, 0xF, true));
    v += __int_as_float(__builtin_amdgcn_update_dpp(
        0, __float_as_int(v), 0x4E, 0xF, 0xF, true));
    v += __int_as_float(__builtin_amdgcn_update_dpp(
        0, __float_as_int(v), 0x124, 0xF, 0xF, true));
    v += __int_as_float(__builtin_amdgcn_update_dpp(
        0, __float_as_int(v), 0x128, 0xF, 0xF, true));
    return v;
}
// sum over each 32-lane half
__device__ __forceinline__ float red32(float v) {
    v = dpp_add16(v);
    v += __shfl_xor(v, 16, 64);
    return v;
}

// One quad = loads xA (rows 0,1 of quad) and xB (rows 2,3).
// eA/eB are half-uniform (lane<32: even row of pair, lane>=32: odd row).
#define COMPUTE2(xA, xB) do {                                            \
    float pA0 = DOT4(xA, w0), pB0 = DOT4(xB, w0);                        \
    float pA1 = DOT4(xA, w1), pB1 = DOT4(xB, w1);                        \
    float pA2 = DOT4(xA, w2), pB2 = DOT4(xB, w2);                        \
    float pA3 = DOT4(xA, w3), pB3 = DOT4(xB, w3);                        \
    pA0 = red32(pA0); pB0 = red32(pB0);                                  \
    pA1 = red32(pA1); pB1 = red32(pB1);                                  \
    pA2 = red32(pA2); pB2 = red32(pB2);                                  \
    pA3 = red32(pA3); pB3 = red32(pB3);                                  \
    const float eA0 = __builtin_exp2f(pA0), eB0 = __builtin_exp2f(pB0);  \
    const float eA1 = __builtin_exp2f(pA1), eB1 = __builtin_exp2f(pB1);  \
    const float eA2 = __builtin_exp2f(pA2), eB2 = __builtin_exp2f(pB2);  \
    const float eA3 = __builtin_exp2f(pA3), eB3 = __builtin_exp2f(pB3);  \
    s0 += eA0 + eB0; s1 += eA1 + eB1;                                    \
    s2 += eA2 + eB2; s3 += eA3 + eB3;                                    \
    a0 += (xA) * eA0 + (xB) * eB0;                                       \
    a1 += (xA) * eA1 + (xB) * eB1;                                       \
    a2 += (xA) * eA2 + (xB) * eB2;                                       \
    a3 += (xA) * eA3 + (xB) * eB3;                                       \
} while (0)

// Flush: merge lane l with l^32 (the other row-parity holding the same dims),
// then plain coalesced stores. No atomics.
#define FLUSH_STORE(seg) do {                                            \
    float t0 = s0 + __shfl_xor(s0, 32, 64);                              \
    float t1 = s1 + __shfl_xor(s1, 32, 64);                              \
    float t2 = s2 + __shfl_xor(s2, 32, 64);                              \
    float t3 = s3 + __shfl_xor(s3, 32, 64);                              \
    f32x4 r0 = a0, r1 = a1, r2 = a2, r3 = a3;                            \
    _Pragma("unroll")                                                    \
    for (int j = 0; j < 4; ++j) {                                        \
        r0[j] += __shfl_xor(r0[j], 32, 64);                              \
        r1[j] += __shfl_xor(r1[j], 32, 64);                              \
        r2[j] += __shfl_xor(r2[j], 32, 64);                              \
        r3[j] += __shfl_xor(r3[j], 32, 64);                              \
    }                                                                    \
    const size_t ent_ = (size_t)wave * 2 + (nflushed < 1 ? 0 : 1);       \
    float* bp_ = pouth + ent_ * 512 + 4 * (lane & 31);                   \
    if (lane < 32) {                                                     \
        *reinterpret_cast<f32x4*>(bp_ + 0)   = r0;                       \
        *reinterpret_cast<f32x4*>(bp_ + 128) = r1;                       \
    } else {                                                             \
        *reinterpret_cast<f32x4*>(bp_ + 256) = r2;                       \
        *reinterpret_cast<f32x4*>(bp_ + 384) = r3;                       \
    }                                                                    \
    if (lane == 0) {                                                     \
        psum[ent_ * 4 + 0] = t0; psum[ent_ * 4 + 1] = t1;                \
        psum[ent_ * 4 + 2] = t2; psum[ent_ * 4 + 3] = t3;                \
        pseg[ent_] = (seg);                                              \
    }                                                                    \
    nflushed++;                                                          \
    a0 = Z4; a1 = Z4; a2 = Z4; a3 = Z4;                                  \
    s0 = 0.f; s1 = 0.f; s2 = 0.f; s3 = 0.f;                              \
} while (0)

__global__ __launch_bounds__(256) void attn_agg_pass1(
    const float* __restrict__ x, const float* __restrict__ w,
    const int* __restrict__ batch,
    float* __restrict__ pouth,      // [nent][4*128] partial e*x
    float* __restrict__ psum,       // [nent][4]     partial e sums
    int*   __restrict__ pseg,       // [nent]        segment tag (-1 unused)
    int n, int qpw)
{
    const int tid  = blockIdx.x * blockDim.x + threadIdx.x;
    const int wave = tid >> 6;
    const int lane = threadIdx.x & 63;
    const int hf   = lane >> 5;          // row parity within a 2-row load
    const int dd   = (lane & 31) * 4;    // owned dims

    const int nquads = (n + 3) >> 2;
    const int q0 = wave * qpw;
    if (q0 >= nquads) {
        if (lane == 0) { pseg[(size_t)wave * 2] = -1; pseg[(size_t)wave * 2 + 1] = -1; }
        return;
    }
    const int q1 = min(q0 + qpw, nquads);

    // weights for this lane's 4 dims, all 4 heads; LOG2E folded
    const f32x4 w0 = *reinterpret_cast<const f32x4*>(w + 0 * EDIM + dd) * LOG2E;
    const f32x4 w1 = *reinterpret_cast<const f32x4*>(w + 1 * EDIM + dd) * LOG2E;
    const f32x4 w2 = *reinterpret_cast<const f32x4*>(w + 2 * EDIM + dd) * LOG2E;
    const f32x4 w3 = *reinterpret_cast<const f32x4*>(w + 3 * EDIM + dd) * LOG2E;

    const f32x4 Z4 = {0.f, 0.f, 0.f, 0.f};
    f32x4 a0 = Z4, a1 = Z4, a2 = Z4, a3 = Z4;
    float s0 = 0.f, s1 = 0.f, s2 = 0.f, s3 = 0.f;
    int nflushed = 0;

    const int cellN = min(q1 * 4, n);
    int cur_b = __builtin_amdgcn_readfirstlane(batch[q0 * 4]);
    const int last_b = __builtin_amdgcn_readfirstlane(batch[cellN - 1]);
    const int rem = q1 - q0;

    if (cur_b == last_b && q1 * 4 <= n && rem == QPW) {
        // ---- hot chunk (~98% of waves): one segment, exactly 8 quads.
        // 16 PACKED loads (each = 1KB contiguous: lane l -> byte l*16),
        // all issued before any compute.
        const float* xp = x + (size_t)q0 * 512 + lane * 4;
        const f32x4 xA0 = *reinterpret_cast<const f32x4*>(xp + 0 * 512);
        const f32x4 xB0 = *reinterpret_cast<const f32x4*>(xp + 0 * 512 + 256);
        const f32x4 xA1 = *reinterpret_cast<const f32x4*>(xp + 1 * 512);
        const f32x4 xB1 = *reinterpret_cast<const f32x4*>(xp + 1 * 512 + 256);
        const f32x4 xA2 = *reinterpret_cast<const f32x4*>(xp + 2 * 512);
        const f32x4 xB2 = *reinterpret_cast<const f32x4*>(xp + 2 * 512 + 256);
        const f32x4 xA3 = *reinterpret_cast<const f32x4*>(xp + 3 * 512);
        const f32x4 xB3 = *reinterpret_cast<const f32x4*>(xp + 3 * 512 + 256);
        const f32x4 xA4 = *reinterpret_cast<const f32x4*>(xp + 4 * 512);
        const f32x4 xB4 = *reinterpret_cast<const f32x4*>(xp + 4 * 512 + 256);
        const f32x4 xA5 = *reinterpret_cast<const f32x4*>(xp + 5 * 512);
        const f32x4 xB5 = *reinterpret_cast<const f32x4*>(xp + 5 * 512 + 256);
        const f32x4 xA6 = *reinterpret_cast<const f32x4*>(xp + 6 * 512);
        const f32x4 xB6 = *reinterpret_cast<const f32x4*>(xp + 6 * 512 + 256);
        const f32x4 xA7 = *reinterpret_cast<const f32x4*>(xp + 7 * 512);
        const f32x4 xB7 = *reinterpret_cast<const f32x4*>(xp + 7 * 512 + 256);
        __builtin_amdgcn_sched_barrier(0);   // loads above, compute below
        COMPUTE2(xA0, xB0);
        COMPUTE2(xA1, xB1);
        COMPUTE2(xA2, xB2);
        COMPUTE2(xA3, xB3);
        COMPUTE2(xA4, xB4);
        COMPUTE2(xA5, xB5);
        COMPUTE2(xA6, xB6);
        COMPUTE2(xA7, xB7);
    } else {
        // ---- generic chunk: per-quad segment handling ----
        for (int q = q0; q < q1; ++q) {
            const int rA = q * 4 + hf;          // rows this lane touches
            const int rB = rA + 2;
            const int rowA = min(rA, n - 1);
            const int rowB = min(rB, n - 1);
            const f32x4 xA = *reinterpret_cast<const f32x4*>(
                x + (size_t)rowA * EDIM + dd);
            const f32x4 xB = *reinterpret_cast<const f32x4*>(
                x + (size_t)rowB * EDIM + dd);

            float pA0 = DOT4(xA, w0), pB0 = DOT4(xB, w0);
            float pA1 = DOT4(xA, w1), pB1 = DOT4(xB, w1);
            float pA2 = DOT4(xA, w2), pB2 = DOT4(xB, w2);
            float pA3 = DOT4(xA, w3), pB3 = DOT4(xB, w3);
            pA0 = red32(pA0); pB0 = red32(pB0);
            pA1 = red32(pA1); pB1 = red32(pB1);
            pA2 = red32(pA2); pB2 = red32(pB2);
            pA3 = red32(pA3); pB3 = red32(pB3);
            const float eA0 = __builtin_exp2f(pA0), eB0 = __builtin_exp2f(pB0);
            const float eA1 = __builtin_exp2f(pA1), eB1 = __builtin_exp2f(pB1);
            const float eA2 = __builtin_exp2f(pA2), eB2 = __builtin_exp2f(pB2);
            const float eA3 = __builtin_exp2f(pA3), eB3 = __builtin_exp2f(pB3);

            const bool full = (q * 4 + 3 < n);
            const int  b3   = __builtin_amdgcn_readfirstlane(batch[min(q * 4 + 3, n - 1)]);

            if (full && b3 == cur_b) {
                s0 += eA0 + eB0; s1 += eA1 + eB1;
                s2 += eA2 + eB2; s3 += eA3 + eB3;
                a0 += xA * eA0 + xB * eB0;
                a1 += xA * eA1 + xB * eB1;
                a2 += xA * eA2 + xB * eB2;
                a3 += xA * eA3 + xB * eB3;
            } else {
                // boundary/tail quad: masked accumulate old seg, flush, new seg
                const int bA = (rA < n) ? batch[rA] : -2;
                const int bB = (rB < n) ? batch[rB] : -2;
                const bool mA1 = (bA == cur_b), mB1 = (bB == cur_b);
                {
                    const float fA = mA1 ? 1.f : 0.f, fB = mB1 ? 1.f : 0.f;
                    s0 += eA0 * fA + eB0 * fB; s1 += eA1 * fA + eB1 * fB;
                    s2 += eA2 * fA + eB2 * fB; s3 += eA3 * fA + eB3 * fB;
                    a0 += xA * (eA0 * fA) + xB * (eB0 * fB);
                    a1 += xA * (eA1 * fA) + xB * (eB1 * fB);
                    a2 += xA * (eA2 * fA) + xB * (eB2 * fB);
                    a3 += xA * (eA3 * fA) + xB * (eB3 * fB);
                }
                FLUSH_STORE(cur_b);
                cur_b = b3;
                {
                    const float fA = (!mA1 && bA == cur_b) ? 1.f : 0.f;
                    const float fB = (!mB1 && bB == cur_b) ? 1.f : 0.f;
                    s0 += eA0 * fA + eB0 * fB; s1 += eA1 * fA + eB1 * fB;
                    s2 += eA2 * fA + eB2 * fB; s3 += eA3 * fA + eB3 * fB;
                    a0 += xA * (eA0 * fA) + xB * (eB0 * fB);
                    a1 += xA * (eA1 * fA) + xB * (eB1 * fB);
                    a2 += xA * (eA2 * fA) + xB * (eB2 * fB);
                    a3 += xA * (eA3 * fA) + xB * (eB3 * fB);
                }
            }
        }
    }

    FLUSH_STORE(cur_b);
    if (lane == 0 && nflushed < 2) pseg[(size_t)wave * 2 + 1] = -1;
}

// Pass 2: one block per segment. Build LDS match-list over slot tags, gather
// partials, then out[b,d] = 0.25 * sum_h outh[b,h,d] / s[b,h].
__global__ __launch_bounds__(512) void attn_agg_finish(
    const float* __restrict__ pouth, const float* __restrict__ psum,
    const int* __restrict__ pseg, float* __restrict__ out, int nent)
{
    const int b = blockIdx.x;            // segment id
    const int t = threadIdx.x;           // 0..511
    const int h = t >> 7, d = t & (EDIM - 1);

    __shared__ int matches[1024];
    __shared__ int nmatch;
    __shared__ float hacc[NHEAD][EDIM];
    if (t == 0) nmatch = 0;
    __syncthreads();

    for (int i = t; i < nent; i += 512) {
        if (pseg[i] == b) {
            int p = atomicAdd(&nmatch, 1);   // LDS atomic — cheap
            if (p < 1024) matches[p] = i;
        }
    }
    __syncthreads();

    float acc = 0.f, sh = 0.f;
    const int nm = min(nmatch, 1024);
    for (int k = 0; k < nm; ++k) {
        const int i = matches[k];
        acc += pouth[(size_t)i * 512 + t];   // t == h*128+d, coalesced
        sh  += psum[(size_t)i * 4 + h];
    }
    hacc[h][d] = (sh > 0.f) ? (acc / sh) : 0.f;
    __syncthreads();

    if (h == 0)
        out[b * EDIM + d] = 0.25f *
            (hacc[0][d] + hacc[1][d] + hacc[2][d] + hacc[3][d]);
}

extern "C" void kernel_launch(void* const* d_in, const int* in_sizes, int n_in,
                              void* d_out, int out_size, void* d_ws, size_t ws_size,
                              hipStream_t stream) {
    const float* x     = (const float*)d_in[0];   // [N, 128] f32
    const float* w     = (const float*)d_in[1];   // [4, 128] f32
    const int*   batch = (const int*)d_in[2];     // [N] int (sorted)
    float* out = (float*)d_out;                   // [128, 128] f32

    const int n = in_sizes[0] / EDIM;             // 250000
    const int nquads = (n + 3) >> 2;              // 62500

    const int qpw      = QPW;                     // hot path hardcoded to 8
    const int nw       = (nquads + qpw - 1) / qpw;    // 7813 waves
    const int blocks1  = (nw + 3) / 4;
    const int launched = blocks1 * 4;
    const int nent     = launched * 2;

    float* pouth = (float*)d_ws;                  // [nent][512]
    float* psum  = pouth + (size_t)nent * 512;    // [nent][4]
    int*   pseg  = (int*)(psum + (size_t)nent * 4); // [nent]

    attn_agg_pass1<<<blocks1, 256, 0, stream>>>(x, w, batch, pouth, psum, pseg, n, qpw);
    attn_agg_finish<<<NSEG, 512, 0, stream>>>(pouth, psum, pseg, out, nent);
}